// Round 1
// baseline (2903.782 us; speedup 1.0000x reference)
//
#include <hip/hip_runtime.h>
#include <cstdint>
#include <cstddef>

// Problem constants (from reference)
constexpr int HID  = 3072;   // hidden size (K of GEMM1, N of GEMM2)
constexpr int ITR  = 8192;   // intermediate size
constexpr int MTOK = 8192;   // B*S = 4*2048 tokens

constexpr int BM = 128, BN = 128, BK = 32;

typedef __bf16 bf16x8 __attribute__((ext_vector_type(8)));
typedef float  f32x4  __attribute__((ext_vector_type(4)));

// ---------- helpers ----------

// RNE fp32 -> bf16 bits (inputs are finite; NaN not expected)
__device__ inline unsigned short f2bf(float f) {
  unsigned int u = __float_as_uint(f);
  u = (u + 0x7FFFu + ((u >> 16) & 1u)) >> 16;
  return (unsigned short)u;
}

// async global->LDS, 16B per lane. LDS dest must be wave-uniform; HW writes
// dest + lane*16.
__device__ inline void gl2lds16(const void* g, void* l) {
  __builtin_amdgcn_global_load_lds(
      (const __attribute__((address_space(1))) unsigned int*)(uintptr_t)g,
      (__attribute__((address_space(3))) unsigned int*)(unsigned int)(uintptr_t)l,
      16, 0, 0);
}

// ---------- prep kernels ----------

__global__ __launch_bounds__(256) void cvt_f32_to_bf16(
    const float* __restrict__ in, unsigned short* __restrict__ out, long n8) {
  long i = (long)blockIdx.x * 256 + threadIdx.x;
  if (i >= n8) return;
  const float4* in4 = (const float4*)in;
  float4 a = in4[2 * i], b = in4[2 * i + 1];
  float v[8] = {a.x, a.y, a.z, a.w, b.x, b.y, b.z, b.w};
  unsigned short r[8];
#pragma unroll
  for (int t = 0; t < 8; t++) r[t] = f2bf(v[t]);
  uint4 o;
  o.x = (unsigned int)r[0] | ((unsigned int)r[1] << 16);
  o.y = (unsigned int)r[2] | ((unsigned int)r[3] << 16);
  o.z = (unsigned int)r[4] | ((unsigned int)r[5] << 16);
  o.w = (unsigned int)r[6] | ((unsigned int)r[7] << 16);
  ((uint4*)out)[i] = o;
}

__global__ __launch_bounds__(256) void cvt_i32_to_bf16(
    const int* __restrict__ in, unsigned short* __restrict__ out, long n8) {
  long i = (long)blockIdx.x * 256 + threadIdx.x;
  if (i >= n8) return;
  const int4* in4 = (const int4*)in;
  int4 a = in4[2 * i], b = in4[2 * i + 1];
  int v[8] = {a.x, a.y, a.z, a.w, b.x, b.y, b.z, b.w};
  unsigned short r[8];
#pragma unroll
  for (int t = 0; t < 8; t++) r[t] = f2bf((float)v[t]);  // 0..127: exact in bf16
  uint4 o;
  o.x = (unsigned int)r[0] | ((unsigned int)r[1] << 16);
  o.y = (unsigned int)r[2] | ((unsigned int)r[3] << 16);
  o.z = (unsigned int)r[4] | ((unsigned int)r[5] << 16);
  o.w = (unsigned int)r[6] | ((unsigned int)r[7] << 16);
  ((uint4*)out)[i] = o;
}

// ---------- GEMM: C[M,N] = A[M,K] x B[N,K]^T (bf16 in, fp32 acc) ----------
// FUSE=true : B holds gate rows [n] and up rows [n+ITR]; dual accumulators;
//             epilogue h = silu(g*sg) * (u*su) written bf16 to Hout[M,ITR].
// FUSE=false: epilogue C[m,n] = acc * scales[n], fp32 to Cout[M,N].
template <bool FUSE>
__global__ __launch_bounds__(256) void gemm_bt(
    const unsigned short* __restrict__ A, const unsigned short* __restrict__ B,
    const float* __restrict__ scales, unsigned short* __restrict__ Hout,
    float* __restrict__ Cout, int N, int K) {
  const int tid  = threadIdx.x;
  const int wave = tid >> 6;
  const int lane = tid & 63;
  const int m0 = blockIdx.y * BM;
  const int n0 = blockIdx.x * BN;

  __shared__ __align__(16) unsigned short sA[BM * BK];
  __shared__ __align__(16) unsigned short sB[BN * BK];
  __shared__ __align__(16) unsigned short sU[FUSE ? (BN * BK) : 8];

  // staging: each lane loads 16B; wave covers 16 rows (4 lanes/row), 2 issues
  // per 128-row tile (rows wave*16.. and wave*16+64..)
  const int srow = wave * 16 + (lane >> 2);
  const int scol = (lane & 3) * 8;
  const unsigned short* Ag = A + (size_t)(m0 + srow) * K + scol;
  const unsigned short* Bg = B + (size_t)(n0 + srow) * K + scol;
  const unsigned short* Ug = FUSE ? (B + (size_t)(n0 + ITR + srow) * K + scol) : nullptr;

  f32x4 acc[4][4];
  f32x4 accU[4][4];
#pragma unroll
  for (int i = 0; i < 4; i++)
#pragma unroll
    for (int j = 0; j < 4; j++) {
      acc[i][j] = (f32x4){0.f, 0.f, 0.f, 0.f};
      if constexpr (FUSE) accU[i][j] = (f32x4){0.f, 0.f, 0.f, 0.f};
    }

  const int wr = wave >> 1, wc = wave & 1;
  const int ml = lane & 15;
  const int q  = lane >> 4;
  const int aoff = (wr * 64 + ml) * BK + q * 8;
  const int boff = (wc * 64 + ml) * BK + q * 8;

  for (int k0 = 0; k0 < K; k0 += BK) {
    gl2lds16(Ag,                 &sA[(wave * 16) * BK]);
    gl2lds16(Ag + (size_t)64 * K, &sA[(wave * 16 + 64) * BK]);
    gl2lds16(Bg,                 &sB[(wave * 16) * BK]);
    gl2lds16(Bg + (size_t)64 * K, &sB[(wave * 16 + 64) * BK]);
    if constexpr (FUSE) {
      gl2lds16(Ug,                 &sU[(wave * 16) * BK]);
      gl2lds16(Ug + (size_t)64 * K, &sU[(wave * 16 + 64) * BK]);
    }
    Ag += BK; Bg += BK;
    if constexpr (FUSE) Ug += BK;
    __syncthreads();  // drains vmcnt: staged data visible to all waves

    bf16x8 av[4], bv[4], uv[4];
#pragma unroll
    for (int i = 0; i < 4; i++) av[i] = *(const bf16x8*)&sA[aoff + i * 16 * BK];
#pragma unroll
    for (int j = 0; j < 4; j++) bv[j] = *(const bf16x8*)&sB[boff + j * 16 * BK];
    if constexpr (FUSE) {
#pragma unroll
      for (int j = 0; j < 4; j++) uv[j] = *(const bf16x8*)&sU[boff + j * 16 * BK];
    }
#pragma unroll
    for (int i = 0; i < 4; i++)
#pragma unroll
      for (int j = 0; j < 4; j++) {
        acc[i][j] = __builtin_amdgcn_mfma_f32_16x16x32_bf16(av[i], bv[j], acc[i][j], 0, 0, 0);
        if constexpr (FUSE)
          accU[i][j] = __builtin_amdgcn_mfma_f32_16x16x32_bf16(av[i], uv[j], accU[i][j], 0, 0, 0);
      }
    __syncthreads();  // all reads done before next stage overwrites LDS
  }

  // epilogue. C/D layout: col = lane&15, row = (lane>>4)*4 + reg  [m89/m91]
#pragma unroll
  for (int j = 0; j < 4; j++) {
    const int n = n0 + wc * 64 + j * 16 + ml;
    if constexpr (FUSE) {
      const float sg = scales[n];
      const float su = scales[n + ITR];
#pragma unroll
      for (int i = 0; i < 4; i++) {
        const int mrow = m0 + wr * 64 + i * 16 + q * 4;
#pragma unroll
        for (int r = 0; r < 4; r++) {
          float g = acc[i][j][r] * sg;
          float u = accU[i][j][r] * su;
          float h = (g / (1.f + __expf(-g))) * u;  // silu(g)*u
          Hout[(size_t)(mrow + r) * ITR + n] = f2bf(h);
        }
      }
    } else {
      const float sn = scales[n];
#pragma unroll
      for (int i = 0; i < 4; i++) {
        const int mrow = m0 + wr * 64 + i * 16 + q * 4;
#pragma unroll
        for (int r = 0; r < 4; r++) {
          Cout[(size_t)(mrow + r) * N + n] = acc[i][j][r] * sn;
        }
      }
    }
  }
}

// ---------- launch ----------

extern "C" void kernel_launch(void* const* d_in, const int* in_sizes, int n_in,
                              void* d_out, int out_size, void* d_ws, size_t ws_size,
                              hipStream_t stream) {
  const float* x  = (const float*)d_in[0];  // [4,2048,3072] fp32
  const int*   w1 = (const int*)d_in[1];    // [16384,3072] int32 (int8-valued)
  const float* s1 = (const float*)d_in[2];  // [16384]
  const int*   w2 = (const int*)d_in[3];    // [3072,8192] int32
  const float* s2 = (const float*)d_in[4];  // [3072]
  float* out = (float*)d_out;               // [4,2048,3072] fp32

  // workspace layout (bytes): xbf 50.3MB | w1bf 100.7MB | w2bf 50.3MB | hid 134.2MB
  unsigned short* xbf  = (unsigned short*)d_ws;
  unsigned short* w1bf = xbf  + (size_t)MTOK * HID;   // 25,165,824 elems
  unsigned short* w2bf = w1bf + (size_t)2 * ITR * HID;  // 50,331,648 elems
  unsigned short* hid  = w2bf + (size_t)HID * ITR;    // 25,165,824 elems

  {
    long n8 = (long)MTOK * HID / 8;  // 3,145,728
    cvt_f32_to_bf16<<<(unsigned)(n8 / 256), 256, 0, stream>>>(x, xbf, n8);
  }
  {
    long n8 = (long)2 * ITR * HID / 8;  // 6,291,456
    cvt_i32_to_bf16<<<(unsigned)(n8 / 256), 256, 0, stream>>>(w1, w1bf, n8);
  }
  {
    long n8 = (long)HID * ITR / 8;  // 3,145,728
    cvt_i32_to_bf16<<<(unsigned)(n8 / 256), 256, 0, stream>>>(w2, w2bf, n8);
  }

  // GEMM1 fused: hidden[8192, 8192] = silu(x@Wg^T * sg) * (x@Wu^T * su)
  {
    dim3 grid(ITR / BN, MTOK / BM);  // 64 x 64
    gemm_bt<true><<<grid, 256, 0, stream>>>(xbf, w1bf, s1, hid, nullptr, ITR, HID);
  }
  // GEMM2: out[8192, 3072] = hidden @ Wd^T * sd
  {
    dim3 grid(HID / BN, MTOK / BM);  // 24 x 64
    gemm_bt<false><<<grid, 256, 0, stream>>>(hid, w2bf, s2, nullptr, out, HID, ITR);
  }
}

// Round 2
// 1974.657 us; speedup vs baseline: 1.4705x; 1.4705x over previous
//
#include <hip/hip_runtime.h>
#include <cstdint>
#include <cstddef>

// Problem constants (from reference)
constexpr int HID  = 3072;   // hidden size (K of GEMM1, N of GEMM2)
constexpr int ITR  = 8192;   // intermediate size
constexpr int MTOK = 8192;   // B*S = 4*2048 tokens

constexpr int BM = 128, BN = 128, BK = 32;

typedef __bf16 bf16x8 __attribute__((ext_vector_type(8)));
typedef float  f32x4  __attribute__((ext_vector_type(4)));

// ---------- helpers ----------

// RNE fp32 -> bf16 bits (inputs are finite; NaN not expected)
__device__ inline unsigned short f2bf(float f) {
  unsigned int u = __float_as_uint(f);
  u = (u + 0x7FFFu + ((u >> 16) & 1u)) >> 16;
  return (unsigned short)u;
}

// async global->LDS, 16B per lane. LDS dest is wave-uniform base; HW writes
// dest + lane*16.
__device__ inline void gl2lds16(const void* g, void* l) {
  __builtin_amdgcn_global_load_lds(
      (const __attribute__((address_space(1))) unsigned int*)(uintptr_t)g,
      (__attribute__((address_space(3))) unsigned int*)(unsigned int)(uintptr_t)l,
      16, 0, 0);
}

// ---------- prep kernels ----------

__global__ __launch_bounds__(256) void cvt_f32_to_bf16(
    const float* __restrict__ in, unsigned short* __restrict__ out, long n8) {
  long i = (long)blockIdx.x * 256 + threadIdx.x;
  if (i >= n8) return;
  const float4* in4 = (const float4*)in;
  float4 a = in4[2 * i], b = in4[2 * i + 1];
  float v[8] = {a.x, a.y, a.z, a.w, b.x, b.y, b.z, b.w};
  unsigned short r[8];
#pragma unroll
  for (int t = 0; t < 8; t++) r[t] = f2bf(v[t]);
  uint4 o;
  o.x = (unsigned int)r[0] | ((unsigned int)r[1] << 16);
  o.y = (unsigned int)r[2] | ((unsigned int)r[3] << 16);
  o.z = (unsigned int)r[4] | ((unsigned int)r[5] << 16);
  o.w = (unsigned int)r[6] | ((unsigned int)r[7] << 16);
  ((uint4*)out)[i] = o;
}

// plain int32 -> bf16 (values 0..127 are exact in bf16)
__global__ __launch_bounds__(256) void cvt_i32_to_bf16(
    const int* __restrict__ in, unsigned short* __restrict__ out, long n8) {
  long i = (long)blockIdx.x * 256 + threadIdx.x;
  if (i >= n8) return;
  const int4* in4 = (const int4*)in;
  int4 a = in4[2 * i], b = in4[2 * i + 1];
  int v[8] = {a.x, a.y, a.z, a.w, b.x, b.y, b.z, b.w};
  unsigned short r[8];
#pragma unroll
  for (int t = 0; t < 8; t++) r[t] = f2bf((float)v[t]);
  uint4 o;
  o.x = (unsigned int)r[0] | ((unsigned int)r[1] << 16);
  o.y = (unsigned int)r[2] | ((unsigned int)r[3] << 16);
  o.z = (unsigned int)r[4] | ((unsigned int)r[5] << 16);
  o.w = (unsigned int)r[6] | ((unsigned int)r[7] << 16);
  ((uint4*)out)[i] = o;
}

// int32 -> bf16 with gate/up 16-row interleave:
// out row R:  q=R>>5, rm=R&31;  orig = rm<16 ? q*16+rm : ITR + q*16 + (rm-16)
// so out rows = [g0..g15, u0..u15, g16..g31, u16..u31, ...]
__global__ __launch_bounds__(256) void cvt_w1_perm(
    const int* __restrict__ in, unsigned short* __restrict__ out, long n8) {
  long i = (long)blockIdx.x * 256 + threadIdx.x;
  if (i >= n8) return;
  const int R  = (int)(i / (HID / 8));
  const int c8 = (int)(i % (HID / 8));
  const int q = R >> 5, rm = R & 31;
  const int orig = (rm < 16) ? (q * 16 + rm) : (ITR + q * 16 + (rm - 16));
  const int4* in4 = (const int4*)(in + (size_t)orig * HID + c8 * 8);
  int4 a = in4[0], b = in4[1];
  int v[8] = {a.x, a.y, a.z, a.w, b.x, b.y, b.z, b.w};
  unsigned short r[8];
#pragma unroll
  for (int t = 0; t < 8; t++) r[t] = f2bf((float)v[t]);
  uint4 o;
  o.x = (unsigned int)r[0] | ((unsigned int)r[1] << 16);
  o.y = (unsigned int)r[2] | ((unsigned int)r[3] << 16);
  o.z = (unsigned int)r[4] | ((unsigned int)r[5] << 16);
  o.w = (unsigned int)r[6] | ((unsigned int)r[7] << 16);
  *(uint4*)(out + (size_t)R * HID + c8 * 8) = o;
}

// ---------- shared GEMM body: C[M,N] = A[M,K] x B[N,K]^T, bf16 in, fp32 acc ----
// m97 structure: 128x128 tile, 4 waves as 2x2 of 64x64, 4x4 f32x4 acc/wave.

// GEMM1 (fused): B is the PERMUTED gate/up weight (N = 2*ITR interleaved in
// 16-row groups). j-tiles pair as (gate, up) in the same lane; epilogue does
// silu(g*sg)*(u*su) -> bf16 Hout[M, ITR].
__global__ __launch_bounds__(256, 2) void gemm1_fused(
    const unsigned short* __restrict__ A, const unsigned short* __restrict__ B,
    const float* __restrict__ scales, unsigned short* __restrict__ Hout) {
  const int K = HID;
  const int tid  = threadIdx.x;
  const int wave = tid >> 6;
  const int lane = tid & 63;
  const int m0 = blockIdx.y * BM;
  const int n0 = blockIdx.x * BN;  // interleaved-column space [0, 2*ITR)

  __shared__ __align__(16) unsigned short sA[BM * BK];
  __shared__ __align__(16) unsigned short sB[BN * BK];

  const int srow = wave * 16 + (lane >> 2);
  const int scol = (lane & 3) * 8;
  const unsigned short* Ag = A + (size_t)(m0 + srow) * K + scol;
  const unsigned short* Bg = B + (size_t)(n0 + srow) * K + scol;

  f32x4 acc[4][4];
#pragma unroll
  for (int i = 0; i < 4; i++)
#pragma unroll
    for (int j = 0; j < 4; j++) acc[i][j] = (f32x4){0.f, 0.f, 0.f, 0.f};

  const int wr = wave >> 1, wc = wave & 1;
  const int ml = lane & 15;
  const int q  = lane >> 4;
  const int aoff = (wr * 64 + ml) * BK + q * 8;
  const int boff = (wc * 64 + ml) * BK + q * 8;

  for (int k0 = 0; k0 < K; k0 += BK) {
    gl2lds16(Ag,                  &sA[(wave * 16) * BK]);
    gl2lds16(Ag + (size_t)64 * K, &sA[(wave * 16 + 64) * BK]);
    gl2lds16(Bg,                  &sB[(wave * 16) * BK]);
    gl2lds16(Bg + (size_t)64 * K, &sB[(wave * 16 + 64) * BK]);
    Ag += BK; Bg += BK;
    __syncthreads();

    bf16x8 av[4], bv[4];
#pragma unroll
    for (int i = 0; i < 4; i++) av[i] = *(const bf16x8*)&sA[aoff + i * 16 * BK];
#pragma unroll
    for (int j = 0; j < 4; j++) bv[j] = *(const bf16x8*)&sB[boff + j * 16 * BK];
#pragma unroll
    for (int i = 0; i < 4; i++)
#pragma unroll
      for (int j = 0; j < 4; j++)
        acc[i][j] = __builtin_amdgcn_mfma_f32_16x16x32_bf16(av[i], bv[j], acc[i][j], 0, 0, 0);
    __syncthreads();
  }

  // Epilogue: j-tile pairs (0,1) and (2,3) are (gate, up) for the same 16
  // hidden columns. hidden col = (n0 + wc*64)/2 + jp*16 + ml.
  // C/D layout: col = lane&15, row = (lane>>4)*4 + reg  [m89/m91]
#pragma unroll
  for (int jp = 0; jp < 2; jp++) {
    const int hcol = (n0 + wc * 64) / 2 + jp * 16 + ml;
    const float sg = scales[hcol];
    const float su = scales[ITR + hcol];
#pragma unroll
    for (int i = 0; i < 4; i++) {
      const int mrow = m0 + wr * 64 + i * 16 + q * 4;
#pragma unroll
      for (int r = 0; r < 4; r++) {
        float g = acc[i][2 * jp][r] * sg;
        float u = acc[i][2 * jp + 1][r] * su;
        float h = (g / (1.f + __expf(-g))) * u;  // silu(g)*u
        Hout[(size_t)(mrow + r) * ITR + hcol] = f2bf(h);
      }
    }
  }
}

// GEMM2: plain, epilogue C[m,n] = acc * scales[n] (fp32 out). N=HID, K=ITR.
__global__ __launch_bounds__(256, 2) void gemm2(
    const unsigned short* __restrict__ A, const unsigned short* __restrict__ B,
    const float* __restrict__ scales, float* __restrict__ Cout) {
  const int N = HID, K = ITR;
  const int tid  = threadIdx.x;
  const int wave = tid >> 6;
  const int lane = tid & 63;
  const int m0 = blockIdx.y * BM;
  const int n0 = blockIdx.x * BN;

  __shared__ __align__(16) unsigned short sA[BM * BK];
  __shared__ __align__(16) unsigned short sB[BN * BK];

  const int srow = wave * 16 + (lane >> 2);
  const int scol = (lane & 3) * 8;
  const unsigned short* Ag = A + (size_t)(m0 + srow) * K + scol;
  const unsigned short* Bg = B + (size_t)(n0 + srow) * K + scol;

  f32x4 acc[4][4];
#pragma unroll
  for (int i = 0; i < 4; i++)
#pragma unroll
    for (int j = 0; j < 4; j++) acc[i][j] = (f32x4){0.f, 0.f, 0.f, 0.f};

  const int wr = wave >> 1, wc = wave & 1;
  const int ml = lane & 15;
  const int q  = lane >> 4;
  const int aoff = (wr * 64 + ml) * BK + q * 8;
  const int boff = (wc * 64 + ml) * BK + q * 8;

  for (int k0 = 0; k0 < K; k0 += BK) {
    gl2lds16(Ag,                  &sA[(wave * 16) * BK]);
    gl2lds16(Ag + (size_t)64 * K, &sA[(wave * 16 + 64) * BK]);
    gl2lds16(Bg,                  &sB[(wave * 16) * BK]);
    gl2lds16(Bg + (size_t)64 * K, &sB[(wave * 16 + 64) * BK]);
    Ag += BK; Bg += BK;
    __syncthreads();

    bf16x8 av[4], bv[4];
#pragma unroll
    for (int i = 0; i < 4; i++) av[i] = *(const bf16x8*)&sA[aoff + i * 16 * BK];
#pragma unroll
    for (int j = 0; j < 4; j++) bv[j] = *(const bf16x8*)&sB[boff + j * 16 * BK];
#pragma unroll
    for (int i = 0; i < 4; i++)
#pragma unroll
      for (int j = 0; j < 4; j++)
        acc[i][j] = __builtin_amdgcn_mfma_f32_16x16x32_bf16(av[i], bv[j], acc[i][j], 0, 0, 0);
    __syncthreads();
  }

#pragma unroll
  for (int j = 0; j < 4; j++) {
    const int n = n0 + wc * 64 + j * 16 + ml;
    const float sn = scales[n];
#pragma unroll
    for (int i = 0; i < 4; i++) {
      const int mrow = m0 + wr * 64 + i * 16 + q * 4;
#pragma unroll
      for (int r = 0; r < 4; r++) {
        Cout[(size_t)(mrow + r) * N + n] = acc[i][j][r] * sn;
      }
    }
  }
}

// ---------- launch ----------

extern "C" void kernel_launch(void* const* d_in, const int* in_sizes, int n_in,
                              void* d_out, int out_size, void* d_ws, size_t ws_size,
                              hipStream_t stream) {
  const float* x  = (const float*)d_in[0];  // [4,2048,3072] fp32
  const int*   w1 = (const int*)d_in[1];    // [16384,3072] int32 (int8-valued)
  const float* s1 = (const float*)d_in[2];  // [16384]
  const int*   w2 = (const int*)d_in[3];    // [3072,8192] int32
  const float* s2 = (const float*)d_in[4];  // [3072]
  float* out = (float*)d_out;               // [4,2048,3072] fp32

  // workspace: xbf 50.3MB | w1bf(perm) 100.7MB | w2bf 50.3MB | hid 134.2MB
  unsigned short* xbf  = (unsigned short*)d_ws;
  unsigned short* w1bf = xbf  + (size_t)MTOK * HID;
  unsigned short* w2bf = w1bf + (size_t)2 * ITR * HID;
  unsigned short* hid  = w2bf + (size_t)HID * ITR;

  {
    long n8 = (long)MTOK * HID / 8;
    cvt_f32_to_bf16<<<(unsigned)(n8 / 256), 256, 0, stream>>>(x, xbf, n8);
  }
  {
    long n8 = (long)2 * ITR * HID / 8;
    cvt_w1_perm<<<(unsigned)(n8 / 256), 256, 0, stream>>>(w1, w1bf, n8);
  }
  {
    long n8 = (long)HID * ITR / 8;
    cvt_i32_to_bf16<<<(unsigned)(n8 / 256), 256, 0, stream>>>(w2, w2bf, n8);
  }

  // GEMM1 fused: hidden[8192,8192] = silu(x@Wg^T*sg) * (x@Wu^T*su)
  {
    dim3 grid(2 * ITR / BN, MTOK / BM);  // 128 x 64
    gemm1_fused<<<grid, 256, 0, stream>>>(xbf, w1bf, s1, hid);
  }
  // GEMM2: out[8192,3072] = hidden @ Wd^T * sd
  {
    dim3 grid(HID / BN, MTOK / BM);  // 24 x 64
    gemm2<<<grid, 256, 0, stream>>>(hid, w2bf, s2, out);
  }
}

// Round 3
// 1354.062 us; speedup vs baseline: 2.1445x; 1.4583x over previous
//
#include <hip/hip_runtime.h>
#include <cstdint>
#include <cstddef>

// Problem constants (from reference)
constexpr int HID  = 3072;   // hidden size (K of GEMM1, N of GEMM2)
constexpr int ITR  = 8192;   // intermediate size
constexpr int MTOK = 8192;   // B*S = 4*2048 tokens

constexpr int BM = 128, BN = 128;

typedef __bf16 bf16x8 __attribute__((ext_vector_type(8)));
typedef float  f32x4  __attribute__((ext_vector_type(4)));
typedef int    i32x4  __attribute__((ext_vector_type(4)));

// ---------- helpers ----------

// RNE fp32 -> bf16 bits
__device__ inline unsigned short f2bf(float f) {
  unsigned int u = __float_as_uint(f);
  u = (u + 0x7FFFu + ((u >> 16) & 1u)) >> 16;
  return (unsigned short)u;
}

// async global->LDS, 16B per lane. LDS dest is wave-uniform base; HW writes
// dest + lane*16.
__device__ inline void gl2lds16(const void* g, void* l) {
  __builtin_amdgcn_global_load_lds(
      (const __attribute__((address_space(1))) unsigned int*)(uintptr_t)g,
      (__attribute__((address_space(3))) unsigned int*)(unsigned int)(uintptr_t)l,
      16, 0, 0);
}

// ---------- prep kernels ----------

// per-token int8 quantization of x: one block per row of 3072.
// qs[row] = absmax/127;  xq = round(x/qs)
__global__ __launch_bounds__(256) void quant_x(
    const float* __restrict__ x, signed char* __restrict__ xq,
    float* __restrict__ qs) {
  const int row = blockIdx.x;
  const int t = threadIdx.x;
  const int wave = t >> 6, lane = t & 63;
  const float4* xr = (const float4*)(x + (size_t)row * HID);  // 768 float4
  float4 v[3];
  float m = 0.f;
#pragma unroll
  for (int k = 0; k < 3; k++) {
    v[k] = xr[t + 256 * k];
    m = fmaxf(m, fmaxf(fmaxf(fabsf(v[k].x), fabsf(v[k].y)),
                       fmaxf(fabsf(v[k].z), fabsf(v[k].w))));
  }
#pragma unroll
  for (int off = 32; off >= 1; off >>= 1) m = fmaxf(m, __shfl_down(m, off));
  __shared__ float wm[4];
  if (lane == 0) wm[wave] = m;
  __syncthreads();
  const float am = fmaxf(fmaxf(wm[0], wm[1]), fmaxf(wm[2], wm[3]));
  const float scale = am / 127.f;
  const float inv = (am > 1e-30f) ? 127.f / am : 0.f;
  if (t == 0) qs[row] = (am > 1e-30f) ? scale : 1.f;
  int* out = (int*)(xq + (size_t)row * HID);
#pragma unroll
  for (int k = 0; k < 3; k++) {
    int r0 = __float2int_rn(v[k].x * inv);
    int r1 = __float2int_rn(v[k].y * inv);
    int r2 = __float2int_rn(v[k].z * inv);
    int r3 = __float2int_rn(v[k].w * inv);
    out[t + 256 * k] =
        (r0 & 255) | ((r1 & 255) << 8) | ((r2 & 255) << 16) | ((r3 & 255) << 24);
  }
}

// w1 int32 -> int8 with gate/up 16-row interleave:
// out row R: q=R>>5, rm=R&31; orig = rm<16 ? q*16+rm : ITR + q*16 + (rm-16)
__global__ __launch_bounds__(256) void cvt_w1_i8(
    const int* __restrict__ in, signed char* __restrict__ out) {
  const int nw = 2 * ITR * (HID / 4);  // int32-out words
  int i = blockIdx.x * 256 + threadIdx.x;
  if (i >= nw) return;
  const int R  = i / (HID / 4);
  const int c4 = i % (HID / 4);
  const int q = R >> 5, rm = R & 31;
  const int orig = (rm < 16) ? (q * 16 + rm) : (ITR + q * 16 + (rm - 16));
  int4 w = ((const int4*)(in + (size_t)orig * HID))[c4];
  ((int*)out)[(size_t)R * (HID / 4) + c4] =
      (w.x & 255) | ((w.y & 255) << 8) | ((w.z & 255) << 16) | ((w.w & 255) << 24);
}

// w2 int32 -> bf16 (values 0..126 exact in bf16)
__global__ __launch_bounds__(256) void cvt_i32_to_bf16(
    const int* __restrict__ in, unsigned short* __restrict__ out, long n8) {
  long i = (long)blockIdx.x * 256 + threadIdx.x;
  if (i >= n8) return;
  const int4* in4 = (const int4*)in;
  int4 a = in4[2 * i], b = in4[2 * i + 1];
  int v[8] = {a.x, a.y, a.z, a.w, b.x, b.y, b.z, b.w};
  unsigned short r[8];
#pragma unroll
  for (int t = 0; t < 8; t++) r[t] = f2bf((float)v[t]);
  uint4 o;
  o.x = (unsigned int)r[0] | ((unsigned int)r[1] << 16);
  o.y = (unsigned int)r[2] | ((unsigned int)r[3] << 16);
  o.z = (unsigned int)r[4] | ((unsigned int)r[5] << 16);
  o.w = (unsigned int)r[6] | ((unsigned int)r[7] << 16);
  ((uint4*)out)[i] = o;
}

// ---------- GEMM1 (int8): hidden = silu(x@Wg^T*sg*qs) * (x@Wu^T*su*qs) -------
// 128x128 tile, BK=64 int8. B is the permuted gate/up weight (interleaved 16-row
// groups, N-space = 2*ITR). LDS rows are 64B; chunk c of tile-row r is stored at
// slot c ^ ((r>>1)&3) (XOR swizzle; staging loads global chunk (lane&3)^((lane>>3)&3)
// so the wave-uniform-base global_load_lds still lands it at slot lane&3).
__global__ __launch_bounds__(256, 2) void gemm1_i8(
    const signed char* __restrict__ A, const signed char* __restrict__ B,
    const float* __restrict__ qs, const float* __restrict__ scales,
    unsigned short* __restrict__ Hout) {
  const int K = HID;
  const int tid  = threadIdx.x;
  const int wave = tid >> 6;
  const int lane = tid & 63;

  // panel swizzle: PN consecutive n-blocks share weights across all m-blocks
  const int PN = 32, MB = MTOK / BM;  // 64 m-blocks
  const int bid = blockIdx.x;
  const int panel = bid / (PN * MB);
  const int rem = bid - panel * (PN * MB);
  const int nb = panel * PN + (rem % PN);
  const int mb = rem / PN;
  const int m0 = mb * BM;
  const int n0 = nb * BN;  // interleaved-column space [0, 2*ITR)

  __shared__ __align__(16) signed char sA[BM * 64];
  __shared__ __align__(16) signed char sB[BN * 64];

  const int srow  = wave * 16 + (lane >> 2);
  const int chunk = (lane & 3) ^ ((lane >> 3) & 3);  // XOR-swizzled source chunk
  const signed char* Ag = A + (size_t)(m0 + srow) * K + chunk * 16;
  const signed char* Bg = B + (size_t)(n0 + srow) * K + chunk * 16;

  i32x4 acc[4][4];
#pragma unroll
  for (int i = 0; i < 4; i++)
#pragma unroll
    for (int j = 0; j < 4; j++) acc[i][j] = (i32x4){0, 0, 0, 0};

  const int wr = wave >> 1, wc = wave & 1;
  const int ml = lane & 15;
  const int q  = lane >> 4;
  const int slot = (q ^ ((ml >> 1) & 3)) * 16;  // swizzled read slot (bytes)

  for (int k0 = 0; k0 < K; k0 += 64) {
    gl2lds16(Ag,                  &sA[(wave * 16) * 64]);
    gl2lds16(Ag + (size_t)64 * K, &sA[(wave * 16 + 64) * 64]);
    gl2lds16(Bg,                  &sB[(wave * 16) * 64]);
    gl2lds16(Bg + (size_t)64 * K, &sB[(wave * 16 + 64) * 64]);
    Ag += 64; Bg += 64;
    __syncthreads();

    i32x4 av[4], bv[4];
#pragma unroll
    for (int i = 0; i < 4; i++)
      av[i] = *(const i32x4*)&sA[(wr * 64 + i * 16 + ml) * 64 + slot];
#pragma unroll
    for (int j = 0; j < 4; j++)
      bv[j] = *(const i32x4*)&sB[(wc * 64 + j * 16 + ml) * 64 + slot];
#pragma unroll
    for (int i = 0; i < 4; i++)
#pragma unroll
      for (int j = 0; j < 4; j++)
        acc[i][j] = __builtin_amdgcn_mfma_i32_16x16x64_i8(av[i], bv[j], acc[i][j], 0, 0, 0);
    __syncthreads();
  }

  // Epilogue: j pairs (0,1),(2,3) = (gate,up) for the same 16 hidden cols.
  // C/D layout: col = lane&15, row = (lane>>4)*4 + reg
#pragma unroll
  for (int jp = 0; jp < 2; jp++) {
    const int hcol = (n0 + wc * 64) / 2 + jp * 16 + ml;
    const float sg = scales[hcol];
    const float su = scales[ITR + hcol];
#pragma unroll
    for (int i = 0; i < 4; i++) {
      const int mrow = m0 + wr * 64 + i * 16 + q * 4;
#pragma unroll
      for (int r = 0; r < 4; r++) {
        const float rowqs = qs[mrow + r];
        float g = (float)acc[i][2 * jp][r] * sg * rowqs;
        float u = (float)acc[i][2 * jp + 1][r] * su * rowqs;
        float h = (g / (1.f + __expf(-g))) * u;  // silu(g)*u
        Hout[(size_t)(mrow + r) * ITR + hcol] = f2bf(h);
      }
    }
  }
}

// ---------- GEMM2 (bf16): out = hidden @ Wd^T * sd ---------------------------
__global__ __launch_bounds__(256, 2) void gemm2(
    const unsigned short* __restrict__ A, const unsigned short* __restrict__ B,
    const float* __restrict__ scales, float* __restrict__ Cout) {
  const int N = HID, K = ITR, BK = 32;
  const int tid  = threadIdx.x;
  const int wave = tid >> 6;
  const int lane = tid & 63;
  const int m0 = blockIdx.y * BM;
  const int n0 = blockIdx.x * BN;

  __shared__ __align__(16) unsigned short sA[BM * BK];
  __shared__ __align__(16) unsigned short sB[BN * BK];

  const int srow  = wave * 16 + (lane >> 2);
  const int chunk = (lane & 3) ^ ((lane >> 3) & 3);  // XOR-swizzled source chunk
  const unsigned short* Ag = A + (size_t)(m0 + srow) * K + chunk * 8;
  const unsigned short* Bg = B + (size_t)(n0 + srow) * K + chunk * 8;

  f32x4 acc[4][4];
#pragma unroll
  for (int i = 0; i < 4; i++)
#pragma unroll
    for (int j = 0; j < 4; j++) acc[i][j] = (f32x4){0.f, 0.f, 0.f, 0.f};

  const int wr = wave >> 1, wc = wave & 1;
  const int ml = lane & 15;
  const int q  = lane >> 4;
  const int slot = (q ^ ((ml >> 1) & 3)) * 8;  // swizzled read slot (shorts)

  for (int k0 = 0; k0 < K; k0 += BK) {
    gl2lds16(Ag,                  &sA[(wave * 16) * BK]);
    gl2lds16(Ag + (size_t)64 * K, &sA[(wave * 16 + 64) * BK]);
    gl2lds16(Bg,                  &sB[(wave * 16) * BK]);
    gl2lds16(Bg + (size_t)64 * K, &sB[(wave * 16 + 64) * BK]);
    Ag += BK; Bg += BK;
    __syncthreads();

    bf16x8 av[4], bv[4];
#pragma unroll
    for (int i = 0; i < 4; i++)
      av[i] = *(const bf16x8*)&sA[(wr * 64 + i * 16 + ml) * BK + slot];
#pragma unroll
    for (int j = 0; j < 4; j++)
      bv[j] = *(const bf16x8*)&sB[(wc * 64 + j * 16 + ml) * BK + slot];
#pragma unroll
    for (int i = 0; i < 4; i++)
#pragma unroll
      for (int j = 0; j < 4; j++)
        acc[i][j] = __builtin_amdgcn_mfma_f32_16x16x32_bf16(av[i], bv[j], acc[i][j], 0, 0, 0);
    __syncthreads();
  }

#pragma unroll
  for (int j = 0; j < 4; j++) {
    const int n = n0 + wc * 64 + j * 16 + ml;
    const float sn = scales[n];
#pragma unroll
    for (int i = 0; i < 4; i++) {
      const int mrow = m0 + wr * 64 + i * 16 + q * 4;
#pragma unroll
      for (int r = 0; r < 4; r++) {
        Cout[(size_t)(mrow + r) * N + n] = acc[i][j][r] * sn;
      }
    }
  }
}

// ---------- launch ----------

extern "C" void kernel_launch(void* const* d_in, const int* in_sizes, int n_in,
                              void* d_out, int out_size, void* d_ws, size_t ws_size,
                              hipStream_t stream) {
  const float* x  = (const float*)d_in[0];  // [4,2048,3072] fp32
  const int*   w1 = (const int*)d_in[1];    // [16384,3072] int32 (int8-valued)
  const float* s1 = (const float*)d_in[2];  // [16384]
  const int*   w2 = (const int*)d_in[3];    // [3072,8192] int32
  const float* s2 = (const float*)d_in[4];  // [3072]
  float* out = (float*)d_out;               // [4,2048,3072] fp32

  // workspace: xq 25.2MB | qs 32KB | w1q(perm) 50.3MB | w2bf 50.3MB | hid 134.2MB
  signed char* xq  = (signed char*)d_ws;
  float* qs        = (float*)(xq + (size_t)MTOK * HID);
  signed char* w1q = (signed char*)(qs + MTOK);
  unsigned short* w2bf = (unsigned short*)(w1q + (size_t)2 * ITR * HID);
  unsigned short* hid  = w2bf + (size_t)HID * ITR;

  quant_x<<<MTOK, 256, 0, stream>>>(x, xq, qs);
  {
    int nw = 2 * ITR * (HID / 4);
    cvt_w1_i8<<<(nw + 255) / 256, 256, 0, stream>>>(w1, w1q);
  }
  {
    long n8 = (long)HID * ITR / 8;
    cvt_i32_to_bf16<<<(unsigned)(n8 / 256), 256, 0, stream>>>(w2, w2bf, n8);
  }

  // GEMM1 (int8): hidden[8192,8192]
  {
    unsigned nblocks = (2 * ITR / BN) * (MTOK / BM);  // 128 * 64 = 8192
    gemm1_i8<<<nblocks, 256, 0, stream>>>(xq, w1q, qs, s1, hid);
  }
  // GEMM2 (bf16): out[8192,3072]
  {
    dim3 grid(HID / BN, MTOK / BM);  // 24 x 64
    gemm2<<<grid, 256, 0, stream>>>(hid, w2bf, s2, out);
  }
}

// Round 4
// 1164.810 us; speedup vs baseline: 2.4929x; 1.1625x over previous
//
#include <hip/hip_runtime.h>
#include <cstdint>
#include <cstddef>

// Problem constants (from reference)
constexpr int HID  = 3072;   // hidden size (K of GEMM1, N of GEMM2)
constexpr int ITR  = 8192;   // intermediate size
constexpr int MTOK = 8192;   // B*S = 4*2048 tokens

constexpr int BM = 128, BN = 128;

typedef __bf16 bf16x8 __attribute__((ext_vector_type(8)));
typedef float  f32x4  __attribute__((ext_vector_type(4)));
typedef int    i32x4  __attribute__((ext_vector_type(4)));

// ---------- helpers ----------

// RNE fp32 -> bf16 bits
__device__ inline unsigned short f2bf(float f) {
  unsigned int u = __float_as_uint(f);
  u = (u + 0x7FFFu + ((u >> 16) & 1u)) >> 16;
  return (unsigned short)u;
}

// async global->LDS, 16B per lane. LDS dest is wave-uniform base; HW writes
// dest + lane*16.
__device__ inline void gl2lds16(const void* g, void* l) {
  __builtin_amdgcn_global_load_lds(
      (const __attribute__((address_space(1))) unsigned int*)(uintptr_t)g,
      (__attribute__((address_space(3))) unsigned int*)(unsigned int)(uintptr_t)l,
      16, 0, 0);
}

// ---------- prep kernels ----------

// per-token int8 quantization of x: one block per row of 3072.
// qs[row] = absmax/127;  xq = round(x/qs)
__global__ __launch_bounds__(256) void quant_x(
    const float* __restrict__ x, signed char* __restrict__ xq,
    float* __restrict__ qs) {
  const int row = blockIdx.x;
  const int t = threadIdx.x;
  const int wave = t >> 6, lane = t & 63;
  const float4* xr = (const float4*)(x + (size_t)row * HID);  // 768 float4
  float4 v[3];
  float m = 0.f;
#pragma unroll
  for (int k = 0; k < 3; k++) {
    v[k] = xr[t + 256 * k];
    m = fmaxf(m, fmaxf(fmaxf(fabsf(v[k].x), fabsf(v[k].y)),
                       fmaxf(fabsf(v[k].z), fabsf(v[k].w))));
  }
#pragma unroll
  for (int off = 32; off >= 1; off >>= 1) m = fmaxf(m, __shfl_down(m, off));
  __shared__ float wm[4];
  if (lane == 0) wm[wave] = m;
  __syncthreads();
  const float am = fmaxf(fmaxf(wm[0], wm[1]), fmaxf(wm[2], wm[3]));
  const float inv = (am > 1e-30f) ? 127.f / am : 0.f;
  if (t == 0) qs[row] = (am > 1e-30f) ? am / 127.f : 1.f;
  int* out = (int*)(xq + (size_t)row * HID);
#pragma unroll
  for (int k = 0; k < 3; k++) {
    int r0 = __float2int_rn(v[k].x * inv);
    int r1 = __float2int_rn(v[k].y * inv);
    int r2 = __float2int_rn(v[k].z * inv);
    int r3 = __float2int_rn(v[k].w * inv);
    out[t + 256 * k] =
        (r0 & 255) | ((r1 & 255) << 8) | ((r2 & 255) << 16) | ((r3 & 255) << 24);
  }
}

// w1 int32 -> int8 with gate/up 16-row interleave:
// out row R: q=R>>5, rm=R&31; orig = rm<16 ? q*16+rm : ITR + q*16 + (rm-16)
__global__ __launch_bounds__(256) void cvt_w1_i8(
    const int* __restrict__ in, signed char* __restrict__ out) {
  const int nw = 2 * ITR * (HID / 4);  // int32-out words
  int i = blockIdx.x * 256 + threadIdx.x;
  if (i >= nw) return;
  const int R  = i / (HID / 4);
  const int c4 = i % (HID / 4);
  const int q = R >> 5, rm = R & 31;
  const int orig = (rm < 16) ? (q * 16 + rm) : (ITR + q * 16 + (rm - 16));
  int4 w = ((const int4*)(in + (size_t)orig * HID))[c4];
  ((int*)out)[(size_t)R * (HID / 4) + c4] =
      (w.x & 255) | ((w.y & 255) << 8) | ((w.z & 255) << 16) | ((w.w & 255) << 24);
}

// w2 int32 -> int8, layout preserved ([HID, ITR], k contiguous)
__global__ __launch_bounds__(256) void cvt_w2_i8(
    const int* __restrict__ in, signed char* __restrict__ out) {
  const int nw = HID * (ITR / 4);  // 6,291,456 out words
  int i = blockIdx.x * 256 + threadIdx.x;
  if (i >= nw) return;
  int4 w = ((const int4*)in)[i];
  ((int*)out)[i] =
      (w.x & 255) | ((w.y & 255) << 8) | ((w.z & 255) << 16) | ((w.w & 255) << 24);
}

// per-token int8 quantization of hidden (bf16 in): one block per row of 8192.
// single pass: row stays in registers (32 elems/thread).
__global__ __launch_bounds__(256) void quant_h(
    const unsigned short* __restrict__ h, signed char* __restrict__ hq,
    float* __restrict__ qh) {
  const int row = blockIdx.x;
  const int t = threadIdx.x;
  const int wave = t >> 6, lane = t & 63;
  const uint4* hr = (const uint4*)(h + (size_t)row * ITR);  // 1024 uint4
  uint4 v[4];
  float f[32];
  float m = 0.f;
#pragma unroll
  for (int k = 0; k < 4; k++) {
    v[k] = hr[t + 256 * k];
    const unsigned int w[4] = {v[k].x, v[k].y, v[k].z, v[k].w};
#pragma unroll
    for (int j = 0; j < 4; j++) {
      float lo = __uint_as_float(w[j] << 16);
      float hi = __uint_as_float(w[j] & 0xFFFF0000u);
      f[k * 8 + 2 * j]     = lo;
      f[k * 8 + 2 * j + 1] = hi;
      m = fmaxf(m, fmaxf(fabsf(lo), fabsf(hi)));
    }
  }
#pragma unroll
  for (int off = 32; off >= 1; off >>= 1) m = fmaxf(m, __shfl_down(m, off));
  __shared__ float wm[4];
  if (lane == 0) wm[wave] = m;
  __syncthreads();
  const float am = fmaxf(fmaxf(wm[0], wm[1]), fmaxf(wm[2], wm[3]));
  const float inv = (am > 1e-30f) ? 127.f / am : 0.f;
  if (t == 0) qh[row] = (am > 1e-30f) ? am / 127.f : 1.f;
  int* out = (int*)(hq + (size_t)row * ITR);
#pragma unroll
  for (int k = 0; k < 4; k++) {
#pragma unroll
    for (int j = 0; j < 2; j++) {
      int r0 = __float2int_rn(f[k * 8 + 4 * j]     * inv);
      int r1 = __float2int_rn(f[k * 8 + 4 * j + 1] * inv);
      int r2 = __float2int_rn(f[k * 8 + 4 * j + 2] * inv);
      int r3 = __float2int_rn(f[k * 8 + 4 * j + 3] * inv);
      out[(t + 256 * k) * 2 + j] =
          (r0 & 255) | ((r1 & 255) << 8) | ((r2 & 255) << 16) | ((r3 & 255) << 24);
    }
  }
}

// ---------- GEMM1 (int8): hidden = silu(x@Wg^T*sg*qs) * (x@Wu^T*su*qs) -------
// 128x128 tile, BK=64 int8. B is the permuted gate/up weight (interleaved
// 16-row groups, N-space = 2*ITR). XOR-swizzled LDS chunks: 0 bank conflicts.
__global__ __launch_bounds__(256, 2) void gemm1_i8(
    const signed char* __restrict__ A, const signed char* __restrict__ B,
    const float* __restrict__ qs, const float* __restrict__ scales,
    unsigned short* __restrict__ Hout) {
  const int K = HID;
  const int tid  = threadIdx.x;
  const int wave = tid >> 6;
  const int lane = tid & 63;

  // panel swizzle: PN consecutive n-blocks share weights across all m-blocks
  const int PN = 32, MB = MTOK / BM;
  const int bid = blockIdx.x;
  const int panel = bid / (PN * MB);
  const int rem = bid - panel * (PN * MB);
  const int nb = panel * PN + (rem % PN);
  const int mb = rem / PN;
  const int m0 = mb * BM;
  const int n0 = nb * BN;  // interleaved-column space [0, 2*ITR)

  __shared__ __align__(16) signed char sA[BM * 64];
  __shared__ __align__(16) signed char sB[BN * 64];

  const int srow  = wave * 16 + (lane >> 2);
  const int chunk = (lane & 3) ^ ((lane >> 3) & 3);  // XOR-swizzled source chunk
  const signed char* Ag = A + (size_t)(m0 + srow) * K + chunk * 16;
  const signed char* Bg = B + (size_t)(n0 + srow) * K + chunk * 16;

  i32x4 acc[4][4];
#pragma unroll
  for (int i = 0; i < 4; i++)
#pragma unroll
    for (int j = 0; j < 4; j++) acc[i][j] = (i32x4){0, 0, 0, 0};

  const int wr = wave >> 1, wc = wave & 1;
  const int ml = lane & 15;
  const int q  = lane >> 4;
  const int slot = (q ^ ((ml >> 1) & 3)) * 16;  // swizzled read slot (bytes)

  for (int k0 = 0; k0 < K; k0 += 64) {
    gl2lds16(Ag,                  &sA[(wave * 16) * 64]);
    gl2lds16(Ag + (size_t)64 * K, &sA[(wave * 16 + 64) * 64]);
    gl2lds16(Bg,                  &sB[(wave * 16) * 64]);
    gl2lds16(Bg + (size_t)64 * K, &sB[(wave * 16 + 64) * 64]);
    Ag += 64; Bg += 64;
    __syncthreads();

    i32x4 av[4], bv[4];
#pragma unroll
    for (int i = 0; i < 4; i++)
      av[i] = *(const i32x4*)&sA[(wr * 64 + i * 16 + ml) * 64 + slot];
#pragma unroll
    for (int j = 0; j < 4; j++)
      bv[j] = *(const i32x4*)&sB[(wc * 64 + j * 16 + ml) * 64 + slot];
#pragma unroll
    for (int i = 0; i < 4; i++)
#pragma unroll
      for (int j = 0; j < 4; j++)
        acc[i][j] = __builtin_amdgcn_mfma_i32_16x16x64_i8(av[i], bv[j], acc[i][j], 0, 0, 0);
    __syncthreads();
  }

  // Epilogue: j pairs (0,1),(2,3) = (gate,up) for the same 16 hidden cols.
  // C/D layout: col = lane&15, row = (lane>>4)*4 + reg
#pragma unroll
  for (int jp = 0; jp < 2; jp++) {
    const int hcol = (n0 + wc * 64) / 2 + jp * 16 + ml;
    const float sg = scales[hcol];
    const float su = scales[ITR + hcol];
#pragma unroll
    for (int i = 0; i < 4; i++) {
      const int mrow = m0 + wr * 64 + i * 16 + q * 4;
#pragma unroll
      for (int r = 0; r < 4; r++) {
        const float rowqs = qs[mrow + r];
        float g = (float)acc[i][2 * jp][r] * sg * rowqs;
        float u = (float)acc[i][2 * jp + 1][r] * su * rowqs;
        float h = (g / (1.f + __expf(-g))) * u;  // silu(g)*u
        Hout[(size_t)(mrow + r) * ITR + hcol] = f2bf(h);
      }
    }
  }
}

// ---------- GEMM2 (int8): out = (hq @ Wd^T) * sd[n] * qh[m] ------------------
__global__ __launch_bounds__(256, 2) void gemm2_i8(
    const signed char* __restrict__ A, const signed char* __restrict__ B,
    const float* __restrict__ qh, const float* __restrict__ scales,
    float* __restrict__ Cout) {
  const int K = ITR, N = HID;
  const int tid  = threadIdx.x;
  const int wave = tid >> 6;
  const int lane = tid & 63;
  const int m0 = blockIdx.y * BM;
  const int n0 = blockIdx.x * BN;

  __shared__ __align__(16) signed char sA[BM * 64];
  __shared__ __align__(16) signed char sB[BN * 64];

  const int srow  = wave * 16 + (lane >> 2);
  const int chunk = (lane & 3) ^ ((lane >> 3) & 3);
  const signed char* Ag = A + (size_t)(m0 + srow) * K + chunk * 16;
  const signed char* Bg = B + (size_t)(n0 + srow) * K + chunk * 16;

  i32x4 acc[4][4];
#pragma unroll
  for (int i = 0; i < 4; i++)
#pragma unroll
    for (int j = 0; j < 4; j++) acc[i][j] = (i32x4){0, 0, 0, 0};

  const int wr = wave >> 1, wc = wave & 1;
  const int ml = lane & 15;
  const int q  = lane >> 4;
  const int slot = (q ^ ((ml >> 1) & 3)) * 16;

  for (int k0 = 0; k0 < K; k0 += 64) {
    gl2lds16(Ag,                  &sA[(wave * 16) * 64]);
    gl2lds16(Ag + (size_t)64 * K, &sA[(wave * 16 + 64) * 64]);
    gl2lds16(Bg,                  &sB[(wave * 16) * 64]);
    gl2lds16(Bg + (size_t)64 * K, &sB[(wave * 16 + 64) * 64]);
    Ag += 64; Bg += 64;
    __syncthreads();

    i32x4 av[4], bv[4];
#pragma unroll
    for (int i = 0; i < 4; i++)
      av[i] = *(const i32x4*)&sA[(wr * 64 + i * 16 + ml) * 64 + slot];
#pragma unroll
    for (int j = 0; j < 4; j++)
      bv[j] = *(const i32x4*)&sB[(wc * 64 + j * 16 + ml) * 64 + slot];
#pragma unroll
    for (int i = 0; i < 4; i++)
#pragma unroll
      for (int j = 0; j < 4; j++)
        acc[i][j] = __builtin_amdgcn_mfma_i32_16x16x64_i8(av[i], bv[j], acc[i][j], 0, 0, 0);
    __syncthreads();
  }

#pragma unroll
  for (int j = 0; j < 4; j++) {
    const int n = n0 + wc * 64 + j * 16 + ml;
    const float sn = scales[n];
#pragma unroll
    for (int i = 0; i < 4; i++) {
      const int mrow = m0 + wr * 64 + i * 16 + q * 4;
#pragma unroll
      for (int r = 0; r < 4; r++) {
        Cout[(size_t)(mrow + r) * N + n] = (float)acc[i][j][r] * sn * qh[mrow + r];
      }
    }
  }
}

// ---------- launch ----------

extern "C" void kernel_launch(void* const* d_in, const int* in_sizes, int n_in,
                              void* d_out, int out_size, void* d_ws, size_t ws_size,
                              hipStream_t stream) {
  const float* x  = (const float*)d_in[0];  // [4,2048,3072] fp32
  const int*   w1 = (const int*)d_in[1];    // [16384,3072] int32 (int8-valued)
  const float* s1 = (const float*)d_in[2];  // [16384]
  const int*   w2 = (const int*)d_in[3];    // [3072,8192] int32
  const float* s2 = (const float*)d_in[4];  // [3072]
  float* out = (float*)d_out;               // [4,2048,3072] fp32

  // workspace: xq 25.2M | qs 32K | w1q 50.3M | w2q 25.2M | hid(bf16) 134.2M |
  //            hq 67.1M | qh 32K   (total ~302 MB)
  signed char* xq  = (signed char*)d_ws;
  float* qs        = (float*)(xq + (size_t)MTOK * HID);
  signed char* w1q = (signed char*)(qs + MTOK);
  signed char* w2q = w1q + (size_t)2 * ITR * HID;
  unsigned short* hid = (unsigned short*)(w2q + (size_t)HID * ITR);
  signed char* hq  = (signed char*)(hid + (size_t)MTOK * ITR);
  float* qh        = (float*)(hq + (size_t)MTOK * ITR);

  quant_x<<<MTOK, 256, 0, stream>>>(x, xq, qs);
  {
    int nw = 2 * ITR * (HID / 4);
    cvt_w1_i8<<<(nw + 255) / 256, 256, 0, stream>>>(w1, w1q);
  }
  {
    int nw = HID * (ITR / 4);
    cvt_w2_i8<<<(nw + 255) / 256, 256, 0, stream>>>(w2, w2q);
  }

  // GEMM1 (int8): hid[8192,8192] bf16
  {
    unsigned nblocks = (2 * ITR / BN) * (MTOK / BM);  // 8192
    gemm1_i8<<<nblocks, 256, 0, stream>>>(xq, w1q, qs, s1, hid);
  }
  // quantize hidden per token
  quant_h<<<MTOK, 256, 0, stream>>>(hid, hq, qh);
  // GEMM2 (int8): out[8192,3072] fp32
  {
    dim3 grid(HID / BN, MTOK / BM);  // 24 x 64
    gemm2_i8<<<grid, 256, 0, stream>>>(hq, w2q, qh, s2, out);
  }
}